// Round 9
// baseline (436.641 us; speedup 1.0000x reference)
//
#include <hip/hip_runtime.h>
#include <hip/hip_fp16.h>

typedef __attribute__((ext_vector_type(4))) float f32x4;
typedef __attribute__((ext_vector_type(8))) short s16x8;
typedef __attribute__((ext_vector_type(4))) short s16x4;
typedef unsigned short u16;
typedef unsigned int u32;

__device__ __forceinline__ u16 f2bf(float f) {
    union { float f; unsigned u; } x; x.f = f;
    return (u16)((x.u + 0x7fffu + ((x.u >> 16) & 1u)) >> 16);
}

__device__ __forceinline__ void ld16(const void* g, void* l) {
    __builtin_amdgcn_global_load_lds(
        (const __attribute__((address_space(1))) unsigned int*)g,
        (__attribute__((address_space(3))) unsigned int*)l, 16, 0, 0);
}

// raw barrier: ordering fence for memory ops WITHOUT a forced waitcnt drain
#define ABAR() asm volatile("s_barrier" ::: "memory")

// ---------------------------------------------------------------------------
// BK=64 K-step of a 128x256 output tile (2-barrier core — proven best for
// sgemm at 3 blocks/CU; R8 post-mortem: intra-block pipelining is redundant
// when 12 waves/CU already overlap across blocks).
// ---------------------------------------------------------------------------
__device__ __forceinline__ void kstep64(const u16* gA, const u16* gB, const u16* gC,
                                        long lda, long ldb,
                                        u16* sA, u16* sB,
                                        int wm, int wn, int lm, int lg,
                                        f32x4 acc0[4][4], f32x4 acc1[4][4])
{
    const int t = threadIdx.x;
    __syncthreads();                 // previous iter's readers done
#pragma unroll
    for (int p = 0; p < 4; p++) {
        ld16(gA + (long)p * 32 * lda, sA + p * 2048 + t * 8);
        ld16(gB + (long)p * 32 * ldb, sB + p * 2048 + t * 8);
        ld16(gC + (long)p * 32 * ldb, sB + 8192 + p * 2048 + t * 8);
    }
    __syncthreads();                 // drains vmcnt for global_load_lds

#pragma unroll
    for (int s = 0; s < 2; s++) {
        s16x8 af[4], bf[4], cf[4];
        const int co = (((s * 4 + lg) ^ (lm & 7)) << 3);
#pragma unroll
        for (int i = 0; i < 4; i++) {
            af[i] = *(const s16x8*)&sA[(wm + i * 16 + lm) * 64 + co];
            bf[i] = *(const s16x8*)&sB[(wn + i * 16 + lm) * 64 + co];
            cf[i] = *(const s16x8*)&sB[8192 + (wn + i * 16 + lm) * 64 + co];
        }
#pragma unroll
        for (int i = 0; i < 4; i++)
#pragma unroll
            for (int j = 0; j < 4; j++) {
                acc0[i][j] = __builtin_amdgcn_mfma_f32_16x16x32_bf16(af[i], bf[j], acc0[i][j], 0, 0, 0);
                acc1[i][j] = __builtin_amdgcn_mfma_f32_16x16x32_bf16(af[i], cf[j], acc1[i][j], 0, 0, 0);
            }
    }
}

// Contiguous-K core: C[m][n] = sum_k A[m][k]*B[n][k] for n in two 128-tiles.
__device__ __forceinline__ void gemm_core64(const u16* A, long lda,
                                            const u16* B0, const u16* B1, long ldb,
                                            int m0, int kEnd,
                                            f32x4 acc0[4][4], f32x4 acc1[4][4],
                                            u16* sA, u16* sB)
{
    const int t    = threadIdx.x;
    const int lane = t & 63;
    const int wave = t >> 6;
    const int wm   = (wave & 1) << 6;
    const int wn   = (wave >> 1) << 6;
    const int lm   = lane & 15;
    const int lg   = lane >> 4;
    const int sr   = t >> 3;                              // staging row 0..31
    const int sc   = (((t & 7) ^ ((t >> 3) & 7)) << 3);   // swizzled chunk
    const u16* gA0 = A + (long)(m0 + sr) * lda + sc;
    const u16* gB0 = B0 + (long)sr * ldb + sc;
    const u16* gC0 = B1 + (long)sr * ldb + sc;

    for (int k0 = 0; k0 < kEnd; k0 += 64)
        kstep64(gA0 + k0, gB0 + k0, gC0 + k0, lda, ldb,
                sA, sB, wm, wn, lm, lg, acc0, acc1);
}

// ---------------------------------------------------------------------------
// Fused conversions + l-zero in ONE dispatch.
// ---------------------------------------------------------------------------
__global__ __launch_bounds__(256) void convert_all(const float* __restrict__ X,
                                                   const float* __restrict__ Wk,
                                                   const float* __restrict__ Wq,
                                                   const float* __restrict__ Wv,
                                                   u16* __restrict__ Xb,
                                                   u16* __restrict__ Wkt,
                                                   u16* __restrict__ Wqt,
                                                   u16* __restrict__ Wvt,
                                                   float* __restrict__ l) {
    __shared__ u16 tile[64][65];
    const int bid = blockIdx.x;
    const int t   = threadIdx.x;

    if (bid < 16384) {
        long idx = ((long)bid * 256 + t) * 4;
        f32x4 v = *(const f32x4*)&X[idx];
        s16x4 o;
        o.x = (short)f2bf(v.x); o.y = (short)f2bf(v.y);
        o.z = (short)f2bf(v.z); o.w = (short)f2bf(v.w);
        *(s16x4*)&Xb[idx] = o;
        return;
    }
    if (bid == 17152) {
        f32x4 z = {0.0f, 0.0f, 0.0f, 0.0f};
#pragma unroll
        for (int i = 0; i < 4; i++)
            *(f32x4*)&l[(i * 256 + t) * 4] = z;
        return;
    }
    const int wb = bid - 16384;
    const int by = wb >> 8;          // 0:Wk 1:Wq 2:Wv
    const int bxx = wb & 255;
    const float* W; u16* O;
    if (by == 0)      { W = Wk; O = Wkt; }
    else if (by == 1) { W = Wq; O = Wqt; }
    else              { W = Wv; O = Wvt; }
    int k0 = (bxx >> 4) << 6, n0 = (bxx & 15) << 6;
    int rr = t >> 4, cc = (t & 15) << 2;
#pragma unroll
    for (int i = 0; i < 4; i++) {
        int row = rr + i * 16;
        f32x4 v = *(const f32x4*)&W[(long)(k0 + row) * 1024 + n0 + cc];
        tile[row][cc + 0] = f2bf(v.x); tile[row][cc + 1] = f2bf(v.y);
        tile[row][cc + 2] = f2bf(v.z); tile[row][cc + 3] = f2bf(v.w);
    }
    __syncthreads();
#pragma unroll
    for (int i = 0; i < 4; i++) {
        int row = rr + i * 16;
        s16x4 pk;
        pk.x = (short)tile[cc + 0][row]; pk.y = (short)tile[cc + 1][row];
        pk.z = (short)tile[cc + 2][row]; pk.w = (short)tile[cc + 3][row];
        *(s16x4*)&O[(long)(n0 + row) * 1024 + k0 + cc] = pk;
    }
}

// ---------------------------------------------------------------------------
// Shared 8-phase 256x256 single-barrier GEMM main loop (validated R3/R5 on
// proj_all8). One barrier per phase; counted vmcnt(4) at ph3/ph7; s-outer
// MFMA order.
// ---------------------------------------------------------------------------
__device__ __forceinline__ void stage_half64(const u16* gbase, u16* lbase,
                                             int kt, int h, int t) {
    const u16* g = gbase + (long)(h * 128) * 1024 + kt * 64;
    u16* l = lbase + h * 8192 + t * 8;
    ld16(g, l);
    ld16(g + 64 * 1024, l + 4096);
}

__device__ __forceinline__ void read_A8(const u16* sA, int arow, int ih,
                                        int co0, int co1, s16x8 af[4][2]) {
#pragma unroll
    for (int i = 0; i < 4; i++) {
        af[i][0] = *(const s16x8*)&sA[(arow + (ih * 4 + i) * 16) * 64 + co0];
        af[i][1] = *(const s16x8*)&sA[(arow + (ih * 4 + i) * 16) * 64 + co1];
    }
}

__device__ __forceinline__ void read_B4(const u16* sB, int brow, int jp,
                                        int co0, int co1, s16x8 bf[4][2]) {
#pragma unroll
    for (int j = 2 * jp; j < 2 * jp + 2; j++) {
        bf[j][0] = *(const s16x8*)&sB[(brow + j * 16) * 64 + co0];
        bf[j][1] = *(const s16x8*)&sB[(brow + j * 16) * 64 + co1];
    }
}

__device__ __forceinline__ void mfma16q(f32x4 acc[8][4], const s16x8 af[4][2],
                                        const s16x8 bf[4][2], int ih, int jh) {
    __builtin_amdgcn_s_setprio(1);
#pragma unroll
    for (int s = 0; s < 2; s++)          // s OUTER: dep distance 8
#pragma unroll
        for (int i = 0; i < 4; i++)
#pragma unroll
            for (int j = 0; j < 2; j++)
                acc[ih * 4 + i][jh * 2 + j] = __builtin_amdgcn_mfma_f32_16x16x32_bf16(
                    af[i][s], bf[jh * 2 + j][s], acc[ih * 4 + i][jh * 2 + j], 0, 0, 0);
    __builtin_amdgcn_s_setprio(0);
}

__device__ __forceinline__ void gemm256_8ph(const u16* Abase, const u16* Bbase,
                                            u16* lds, int t,
                                            int arow, int brow, int co0, int co1,
                                            f32x4 acc[8][4]) {
    const int sr = t >> 3;
    const int sc = ((t & 7) ^ (sr & 7)) << 3;
    const u16* Ast = Abase + (long)sr * 1024 + sc;
    const u16* Bst = Bbase + (long)sr * 1024 + sc;
    u16* sA0 = lds;
    u16* sA1 = lds + 16384;
    u16* sB0 = lds + 32768;
    u16* sB1 = lds + 49152;

    s16x8 af[4][2], bf[4][2];

    // Prologue: E0.B, E0.A, O0.B (12 loads); vmcnt(4) -> E0 fully staged.
    stage_half64(Bst, sB0, 0, 0, t); stage_half64(Bst, sB0, 0, 1, t);
    stage_half64(Ast, sA0, 0, 0, t); stage_half64(Ast, sA0, 0, 1, t);
    stage_half64(Bst, sB1, 1, 0, t); stage_half64(Bst, sB1, 1, 1, t);
    asm volatile("s_waitcnt vmcnt(4)" ::: "memory");
    ABAR();

#pragma unroll 1
    for (int it = 0; it < 8; it++) {
        const int  tO   = 2 * it + 1;
        const bool more = (it < 7);
        // ph0: E q(0,0); reads A-lo + B01; stage O.A h0
        read_A8(sA0, arow, 0, co0, co1, af);
        read_B4(sB0, brow, 0, co0, co1, bf);
        stage_half64(Ast, sA1, tO, 0, t);
        mfma16q(acc, af, bf, 0, 0);
        ABAR();
        // ph1: E q(0,1); reads B23; stage O.A h1
        read_B4(sB0, brow, 1, co0, co1, bf);
        stage_half64(Ast, sA1, tO, 1, t);
        mfma16q(acc, af, bf, 0, 1);
        ABAR();
        // ph2: E q(1,0); reads A-hi; stage E'.B h0
        read_A8(sA0, arow, 1, co0, co1, af);
        if (more) stage_half64(Bst, sB0, tO + 1, 0, t);
        mfma16q(acc, af, bf, 1, 0);
        ABAR();
        // ph3: E q(1,1); stage E'.B h1; counted vmcnt (O fully staged)
        if (more) stage_half64(Bst, sB0, tO + 1, 1, t);
        mfma16q(acc, af, bf, 1, 1);
        if (more) asm volatile("s_waitcnt vmcnt(4)" ::: "memory");
        else      asm volatile("s_waitcnt vmcnt(0)" ::: "memory");
        ABAR();
        // ph4: O q(0,0); reads A-lo + B01; stage E'.A h0
        read_A8(sA1, arow, 0, co0, co1, af);
        read_B4(sB1, brow, 0, co0, co1, bf);
        if (more) stage_half64(Ast, sA0, tO + 1, 0, t);
        mfma16q(acc, af, bf, 0, 0);
        ABAR();
        // ph5: O q(0,1); reads B23; stage E'.A h1
        read_B4(sB1, brow, 1, co0, co1, bf);
        if (more) stage_half64(Ast, sA0, tO + 1, 1, t);
        mfma16q(acc, af, bf, 0, 1);
        ABAR();
        // ph6: O q(1,0); reads A-hi; stage O'.B h0
        read_A8(sA1, arow, 1, co0, co1, af);
        if (more) stage_half64(Bst, sB1, tO + 2, 0, t);
        mfma16q(acc, af, bf, 1, 0);
        ABAR();
        // ph7: O q(1,1); stage O'.B h1; counted vmcnt (E' staged)
        if (more) stage_half64(Bst, sB1, tO + 2, 1, t);
        mfma16q(acc, af, bf, 1, 1);
        if (more) asm volatile("s_waitcnt vmcnt(4)" ::: "memory");
        ABAR();
    }
}

// ---------------------------------------------------------------------------
// 8-phase 256x256 projection GEMM (validated R3/R5). grid 768 = exactly
// 3 rounds at 1 block/CU (128 KiB LDS).
// ---------------------------------------------------------------------------
__global__ __launch_bounds__(512, 2) void proj_all8(const u16* __restrict__ X,
                                                    const u16* __restrict__ Wqt,
                                                    const u16* __restrict__ Wkt,
                                                    const u16* __restrict__ Wvt,
                                                    u16* __restrict__ Qb,
                                                    u16* __restrict__ Kb,
                                                    u16* __restrict__ Vt) {
    __shared__ u16 lds[65536];                   // 128 KiB
    // XCD-chunked bijective swizzle: 768 = 8 x 96.
    const int bx  = ((blockIdx.x & 7) * 96) + (blockIdx.x >> 3);
    const int z   = bx >> 8;                     // 0:Q 1:K 2:V
    const int rem = bx & 255;
    const int m0  = (rem >> 2) << 8;
    const int n0  = (rem & 3) << 8;
    const u16* Wt = (z == 0) ? Wqt : (z == 1) ? Wkt : Wvt;

    const int t    = threadIdx.x;
    const int lane = t & 63, w = t >> 6;
    const int wr = w >> 2, wc = w & 3;           // 2M x 4N wave grid
    const int lm = lane & 15, lg = lane >> 4;
    const int arow = wr * 128 + lm;
    const int brow = wc * 64 + lm;
    const int co0 = ((lg) ^ (lm & 7)) << 3;
    const int co1 = ((4 + lg) ^ (lm & 7)) << 3;

    f32x4 acc[8][4] = {};
    gemm256_8ph(X + (long)m0 * 1024, Wt + (long)n0 * 1024, lds, t,
                arow, brow, co0, co1, acc);

    if (z < 2) {
        u16* O = (z == 0) ? Qb : Kb;
#pragma unroll
        for (int i = 0; i < 8; i++)
#pragma unroll
            for (int j = 0; j < 4; j++)
#pragma unroll
                for (int r = 0; r < 4; r++) {
                    int row = m0 + wr * 128 + i * 16 + lg * 4 + r;
                    int col = n0 + wc * 64 + j * 16 + lm;
                    O[(long)row * 1024 + col] = f2bf(acc[i][j][r]);
                }
    } else {
#pragma unroll
        for (int i = 0; i < 8; i++)
#pragma unroll
            for (int j = 0; j < 4; j++) {
                int row0 = m0 + wr * 128 + i * 16 + lg * 4;
                int col  = n0 + wc * 64 + j * 16 + lm;
                int b = row0 >> 12, s = row0 & 4095;
                s16x4 p0;
                p0.x = (short)f2bf(acc[i][j][0]); p0.y = (short)f2bf(acc[i][j][1]);
                p0.z = (short)f2bf(acc[i][j][2]); p0.w = (short)f2bf(acc[i][j][3]);
                *(s16x4*)&Vt[(long)b * 4194304 + (long)col * 4096 + s] = p0;
            }
    }
}

// ---------------------------------------------------------------------------
// Fused S-GEMM + softmax-numerator (R5-proven form, reverted from R8's
// kstep32 experiment which regressed 112->117). grid 4*272.
// ---------------------------------------------------------------------------
__global__ __launch_bounds__(256, 2) void sgemm_causal(const u16* __restrict__ Q,
                                                       const u16* __restrict__ K,
                                                       u16* __restrict__ S,
                                                       float* __restrict__ l) {
    __shared__ u16 sA[8192], sB[16384];
    int b  = blockIdx.x / 272;
    int tt = blockIdx.x % 272;
    int it = (int)(2.0f * sqrtf((float)tt + 1.0f)) - 1;
    if (it > 31) it = 31;
    if (it < 0) it = 0;
    while (it < 31 && (((it + 2) * (it + 2)) >> 2) <= tt) ++it;
    while (it > 0 && (((it + 1) * (it + 1)) >> 2) > tt) --it;
    int jp  = tt - (((it + 1) * (it + 1)) >> 2);
    int jt0 = jp * 2, jt1 = jt0 + 1;
    bool valid1 = (jt1 <= it);

    const u16* A  = Q + (long)b * 4194304;
    const u16* Kp = K + (long)b * 4194304;
    f32x4 acc0[4][4] = {}, acc1[4][4] = {};
    gemm_core64(A, 1024, Kp + (long)jt0 * 131072, Kp + (long)jt1 * 131072, 1024,
                it * 128, 1024, acc0, acc1, sA, sB);

    long tribase = (long)(b * 528 + ((it * (it + 1)) >> 1));
    u16* Sp0 = S + (tribase + jt0) * 16384;
    u16* Sp1 = S + (tribase + jt1) * 16384;
    int lane = threadIdx.x & 63, wave = threadIdx.x >> 6;
    int wm = (wave & 1) << 6, wn = (wave >> 1) << 6, lm = lane & 15, lg = lane >> 4;
    const float LOG2E = 1.44269504088896f;

    float rs[4][4];
#pragma unroll
    for (int i = 0; i < 4; i++)
#pragma unroll
        for (int r = 0; r < 4; r++) rs[i][r] = 0.0f;

#pragma unroll
    for (int i = 0; i < 4; i++)
#pragma unroll
        for (int j = 0; j < 4; j++)
#pragma unroll
            for (int r = 0; r < 4; r++) {
                int ri = wm + i * 16 + lg * 4 + r;
                int cj = wn + j * 16 + lm;
                int gi = it * 128 + ri;
                float p0 = (jt0 * 128 + cj > gi) ? 0.0f
                         : exp2f((acc0[i][j][r] * 0.03125f - 16.0f) * LOG2E);
                Sp0[ri * 128 + cj] = f2bf(p0);
                rs[i][r] += p0;
                if (valid1) {
                    float p1 = (jt1 * 128 + cj > gi) ? 0.0f
                             : exp2f((acc1[i][j][r] * 0.03125f - 16.0f) * LOG2E);
                    Sp1[ri * 128 + cj] = f2bf(p1);
                    rs[i][r] += p1;
                }
            }

#pragma unroll
    for (int i = 0; i < 4; i++)
#pragma unroll
        for (int r = 0; r < 4; r++) {
            float s = rs[i][r];
            s += __shfl_xor(s, 1, 64);
            s += __shfl_xor(s, 2, 64);
            s += __shfl_xor(s, 4, 64);
            s += __shfl_xor(s, 8, 64);
            if (lm == 0)
                atomicAdd(&l[b * 4096 + it * 128 + wm + i * 16 + lg * 4 + r], s);
        }
}

// ---------------------------------------------------------------------------
// R9 pv core: BK=64 K-step of a 128x128 tile, single B (no C). 32 KiB LDS.
// Same proven staging/swizzle/read geometry as kstep64, minus the gC tile.
// ---------------------------------------------------------------------------
__device__ __forceinline__ void kstep64_s(const u16* gA, const u16* gB,
                                          long lda, long ldb,
                                          u16* sA, u16* sB,
                                          int wm, int wn, int lm, int lg,
                                          f32x4 acc[4][4])
{
    const int t = threadIdx.x;
    __syncthreads();
#pragma unroll
    for (int p = 0; p < 4; p++) {
        ld16(gA + (long)p * 32 * lda, sA + p * 2048 + t * 8);
        ld16(gB + (long)p * 32 * ldb, sB + p * 2048 + t * 8);
    }
    __syncthreads();

#pragma unroll
    for (int s = 0; s < 2; s++) {
        s16x8 af[4], bf[4];
        const int co = (((s * 4 + lg) ^ (lm & 7)) << 3);
#pragma unroll
        for (int i = 0; i < 4; i++) {
            af[i] = *(const s16x8*)&sA[(wm + i * 16 + lm) * 64 + co];
            bf[i] = *(const s16x8*)&sB[(wn + i * 16 + lm) * 64 + co];
        }
#pragma unroll
        for (int i = 0; i < 4; i++)
#pragma unroll
            for (int j = 0; j < 4; j++)
                acc[i][j] = __builtin_amdgcn_mfma_f32_16x16x32_bf16(af[i], bf[j], acc[i][j], 0, 0, 0);
    }
}

// ---------------------------------------------------------------------------
// R9: O = P @ V, 128 rows x 128 cols per block. grid 1024 = 4 quadrants x
// 256: q = g>>8, i = g&255 -> u = i>>5 (0..7), b = (i>>3)&3, atp = i&7.
// it = {u, 15-u, 16+u, 31-u}[q]: the quadruple (g, g+256, g+512, g+768)
// sums to 66 jt-tiles -> constant per-CU load under the same round-robin
// placement the proven g/g+256 pairing relied on. 32 KiB LDS + bound 4 ->
// 4 blocks/CU, all 1024 resident (16 waves/CU). Work per element and
// K-accumulation order unchanged -> numerics identical.
// ---------------------------------------------------------------------------
__global__ __launch_bounds__(256, 4) void pv_gemm(const u16* __restrict__ P,
                                                  const u16* __restrict__ Vt,
                                                  const float* __restrict__ l,
                                                  float* __restrict__ Out) {
    __shared__ u16 sA[8192], sB[8192];   // 16 KiB + 16 KiB
    const int g = blockIdx.x;
    const int q = g >> 8, i = g & 255;
    const int u = i >> 5;
    const int b = (i >> 3) & 3;
    const int atp = i & 7;
    const int it = (q == 0) ? u : (q == 1) ? (15 - u) : (q == 2) ? (16 + u) : (31 - u);

    const int t    = threadIdx.x;
    const int lane = t & 63;
    const int wave = t >> 6;
    const int wm   = (wave & 1) << 6;
    const int wn   = (wave >> 1) << 6;
    const int lm   = lane & 15;
    const int lg   = lane >> 4;
    const int sr   = t >> 3;
    const int sc   = (((t & 7) ^ ((t >> 3) & 7)) << 3);

    const u16* Pbase = P + (long)(b * 528 + ((it * (it + 1)) >> 1)) * 16384;
    const u16* gA0 = Pbase + (long)sr * 128 + sc;
    const u16* gB0 = Vt + (long)b * 4194304 + (long)(atp * 128 + sr) * 4096 + sc;

    f32x4 acc[4][4] = {};
    for (int jt = 0; jt <= it; jt++) {
        const long aoff = (long)jt * 16384;
        const long boff = (long)jt * 128;
#pragma unroll
        for (int kk = 0; kk < 128; kk += 64)
            kstep64_s(gA0 + aoff + kk, gB0 + boff + kk, 128, 4096,
                      sA, sB, wm, wn, lm, lg, acc);
    }

#pragma unroll
    for (int ii = 0; ii < 4; ii++)
#pragma unroll
        for (int r2 = 0; r2 < 4; r2++) {
            int gi = it * 128 + wm + ii * 16 + lg * 4 + r2;
            float scale = 1.0f / l[b * 4096 + gi];
#pragma unroll
            for (int j = 0; j < 4; j++) {
                int ga = atp * 128 + wn + j * 16 + lm;
                Out[((long)b * 4096 + gi) * 1024 + ga] = acc[ii][j][r2] * scale;
            }
        }
}

// ---------------------------------------------------------------------------
// Workspace layout (bytes):
//   Qb   [0,          33554432)
//   Kb   [33554432,   67108864)
//   Vt   [67108864,  100663296)
//   l    [100663296, 100728832)   fp32 row sums (atomic-accumulated)
//   Xb   [100728832, 134283264)   (dead after proj_all8)
//   Wqt/Wkt/Wvt [134283264, 140574720)  (dead after proj_all8)
//   S/P  [100728832, 169934848)   packed tri tiles (bf16 P), overlays Xb+W
// ---------------------------------------------------------------------------
extern "C" void kernel_launch(void* const* d_in, const int* in_sizes, int n_in,
                              void* d_out, int out_size, void* d_ws, size_t ws_size,
                              hipStream_t stream) {
    const float* X  = (const float*)d_in[0];
    const float* Wk = (const float*)d_in[1];
    const float* Wq = (const float*)d_in[2];
    const float* Wv = (const float*)d_in[3];
    float* Out = (float*)d_out;

    char* w = (char*)d_ws;
    u16*   Qb   = (u16*)(w);
    u16*   Kb   = (u16*)(w + 33554432);
    u16*   Vt   = (u16*)(w + 67108864);
    float* l    = (float*)(w + 100663296);
    u16*   Xb   = (u16*)(w + 100728832);
    u16*   Wqt  = (u16*)(w + 134283264);
    u16*   Wkt  = (u16*)(w + 136380416);
    u16*   Wvt  = (u16*)(w + 138477568);
    u16*   S    = (u16*)(w + 100728832);

    convert_all<<<17153, 256, 0, stream>>>(X, Wk, Wq, Wv, Xb, Wkt, Wqt, Wvt, l);
    proj_all8<<<768, 512, 0, stream>>>(Xb, Wqt, Wkt, Wvt, Qb, Kb, Vt);
    sgemm_causal<<<1088, 256, 0, stream>>>(Qb, Kb, S, l);
    pv_gemm<<<1024, 256, 0, stream>>>(S, Vt, l, Out);
}

// Round 10
// 406.133 us; speedup vs baseline: 1.0751x; 1.0751x over previous
//
#include <hip/hip_runtime.h>
#include <hip/hip_fp16.h>

typedef __attribute__((ext_vector_type(4))) float f32x4;
typedef __attribute__((ext_vector_type(8))) short s16x8;
typedef __attribute__((ext_vector_type(4))) short s16x4;
typedef unsigned short u16;
typedef unsigned int u32;

__device__ __forceinline__ u16 f2bf(float f) {
    union { float f; unsigned u; } x; x.f = f;
    return (u16)((x.u + 0x7fffu + ((x.u >> 16) & 1u)) >> 16);
}

__device__ __forceinline__ void ld16(const void* g, void* l) {
    __builtin_amdgcn_global_load_lds(
        (const __attribute__((address_space(1))) unsigned int*)g,
        (__attribute__((address_space(3))) unsigned int*)l, 16, 0, 0);
}

// raw barrier: ordering fence for memory ops WITHOUT a forced waitcnt drain
#define ABAR() asm volatile("s_barrier" ::: "memory")

// ---------------------------------------------------------------------------
// BK=64 K-step of a 128x256 output tile (2-barrier core, 48 KiB LDS ->
// 3 blocks/CU: proven best for sgemm/pv — 12 waves/CU of cross-block overlap
// makes explicit intra-block pipelining redundant; R6-R9 experiments all
// neutral-or-worse).
// ---------------------------------------------------------------------------
__device__ __forceinline__ void kstep64(const u16* gA, const u16* gB, const u16* gC,
                                        long lda, long ldb,
                                        u16* sA, u16* sB,
                                        int wm, int wn, int lm, int lg,
                                        f32x4 acc0[4][4], f32x4 acc1[4][4])
{
    const int t = threadIdx.x;
    __syncthreads();                 // previous iter's readers done
#pragma unroll
    for (int p = 0; p < 4; p++) {
        ld16(gA + (long)p * 32 * lda, sA + p * 2048 + t * 8);
        ld16(gB + (long)p * 32 * ldb, sB + p * 2048 + t * 8);
        ld16(gC + (long)p * 32 * ldb, sB + 8192 + p * 2048 + t * 8);
    }
    __syncthreads();                 // drains vmcnt for global_load_lds

#pragma unroll
    for (int s = 0; s < 2; s++) {
        s16x8 af[4], bf[4], cf[4];
        const int co = (((s * 4 + lg) ^ (lm & 7)) << 3);
#pragma unroll
        for (int i = 0; i < 4; i++) {
            af[i] = *(const s16x8*)&sA[(wm + i * 16 + lm) * 64 + co];
            bf[i] = *(const s16x8*)&sB[(wn + i * 16 + lm) * 64 + co];
            cf[i] = *(const s16x8*)&sB[8192 + (wn + i * 16 + lm) * 64 + co];
        }
#pragma unroll
        for (int i = 0; i < 4; i++)
#pragma unroll
            for (int j = 0; j < 4; j++) {
                acc0[i][j] = __builtin_amdgcn_mfma_f32_16x16x32_bf16(af[i], bf[j], acc0[i][j], 0, 0, 0);
                acc1[i][j] = __builtin_amdgcn_mfma_f32_16x16x32_bf16(af[i], cf[j], acc1[i][j], 0, 0, 0);
            }
    }
}

// Contiguous-K core: C[m][n] = sum_k A[m][k]*B[n][k] for n in two 128-tiles.
__device__ __forceinline__ void gemm_core64(const u16* A, long lda,
                                            const u16* B0, const u16* B1, long ldb,
                                            int m0, int kEnd,
                                            f32x4 acc0[4][4], f32x4 acc1[4][4],
                                            u16* sA, u16* sB)
{
    const int t    = threadIdx.x;
    const int lane = t & 63;
    const int wave = t >> 6;
    const int wm   = (wave & 1) << 6;
    const int wn   = (wave >> 1) << 6;
    const int lm   = lane & 15;
    const int lg   = lane >> 4;
    const int sr   = t >> 3;                              // staging row 0..31
    const int sc   = (((t & 7) ^ ((t >> 3) & 7)) << 3);   // swizzled chunk
    const u16* gA0 = A + (long)(m0 + sr) * lda + sc;
    const u16* gB0 = B0 + (long)sr * ldb + sc;
    const u16* gC0 = B1 + (long)sr * ldb + sc;

    for (int k0 = 0; k0 < kEnd; k0 += 64)
        kstep64(gA0 + k0, gB0 + k0, gC0 + k0, lda, ldb,
                sA, sB, wm, wn, lm, lg, acc0, acc1);
}

// ---------------------------------------------------------------------------
// Fused conversions + l-zero in ONE dispatch.
// ---------------------------------------------------------------------------
__global__ __launch_bounds__(256) void convert_all(const float* __restrict__ X,
                                                   const float* __restrict__ Wk,
                                                   const float* __restrict__ Wq,
                                                   const float* __restrict__ Wv,
                                                   u16* __restrict__ Xb,
                                                   u16* __restrict__ Wkt,
                                                   u16* __restrict__ Wqt,
                                                   u16* __restrict__ Wvt,
                                                   float* __restrict__ l) {
    __shared__ u16 tile[64][65];
    const int bid = blockIdx.x;
    const int t   = threadIdx.x;

    if (bid < 16384) {
        long idx = ((long)bid * 256 + t) * 4;
        f32x4 v = *(const f32x4*)&X[idx];
        s16x4 o;
        o.x = (short)f2bf(v.x); o.y = (short)f2bf(v.y);
        o.z = (short)f2bf(v.z); o.w = (short)f2bf(v.w);
        *(s16x4*)&Xb[idx] = o;
        return;
    }
    if (bid == 17152) {
        f32x4 z = {0.0f, 0.0f, 0.0f, 0.0f};
#pragma unroll
        for (int i = 0; i < 4; i++)
            *(f32x4*)&l[(i * 256 + t) * 4] = z;
        return;
    }
    const int wb = bid - 16384;
    const int by = wb >> 8;          // 0:Wk 1:Wq 2:Wv
    const int bxx = wb & 255;
    const float* W; u16* O;
    if (by == 0)      { W = Wk; O = Wkt; }
    else if (by == 1) { W = Wq; O = Wqt; }
    else              { W = Wv; O = Wvt; }
    int k0 = (bxx >> 4) << 6, n0 = (bxx & 15) << 6;
    int rr = t >> 4, cc = (t & 15) << 2;
#pragma unroll
    for (int i = 0; i < 4; i++) {
        int row = rr + i * 16;
        f32x4 v = *(const f32x4*)&W[(long)(k0 + row) * 1024 + n0 + cc];
        tile[row][cc + 0] = f2bf(v.x); tile[row][cc + 1] = f2bf(v.y);
        tile[row][cc + 2] = f2bf(v.z); tile[row][cc + 3] = f2bf(v.w);
    }
    __syncthreads();
#pragma unroll
    for (int i = 0; i < 4; i++) {
        int row = rr + i * 16;
        s16x4 pk;
        pk.x = (short)tile[cc + 0][row]; pk.y = (short)tile[cc + 1][row];
        pk.z = (short)tile[cc + 2][row]; pk.w = (short)tile[cc + 3][row];
        *(s16x4*)&O[(long)(n0 + row) * 1024 + k0 + cc] = pk;
    }
}

// ---------------------------------------------------------------------------
// Shared 8-phase 256x256 single-barrier GEMM main loop (validated R3/R5 on
// proj_all8). One barrier per phase; counted vmcnt(4) at ph3/ph7; s-outer
// MFMA order.
// ---------------------------------------------------------------------------
__device__ __forceinline__ void stage_half64(const u16* gbase, u16* lbase,
                                             int kt, int h, int t) {
    const u16* g = gbase + (long)(h * 128) * 1024 + kt * 64;
    u16* l = lbase + h * 8192 + t * 8;
    ld16(g, l);
    ld16(g + 64 * 1024, l + 4096);
}

__device__ __forceinline__ void read_A8(const u16* sA, int arow, int ih,
                                        int co0, int co1, s16x8 af[4][2]) {
#pragma unroll
    for (int i = 0; i < 4; i++) {
        af[i][0] = *(const s16x8*)&sA[(arow + (ih * 4 + i) * 16) * 64 + co0];
        af[i][1] = *(const s16x8*)&sA[(arow + (ih * 4 + i) * 16) * 64 + co1];
    }
}

__device__ __forceinline__ void read_B4(const u16* sB, int brow, int jp,
                                        int co0, int co1, s16x8 bf[4][2]) {
#pragma unroll
    for (int j = 2 * jp; j < 2 * jp + 2; j++) {
        bf[j][0] = *(const s16x8*)&sB[(brow + j * 16) * 64 + co0];
        bf[j][1] = *(const s16x8*)&sB[(brow + j * 16) * 64 + co1];
    }
}

__device__ __forceinline__ void mfma16q(f32x4 acc[8][4], const s16x8 af[4][2],
                                        const s16x8 bf[4][2], int ih, int jh) {
    __builtin_amdgcn_s_setprio(1);
#pragma unroll
    for (int s = 0; s < 2; s++)          // s OUTER: dep distance 8
#pragma unroll
        for (int i = 0; i < 4; i++)
#pragma unroll
            for (int j = 0; j < 2; j++)
                acc[ih * 4 + i][jh * 2 + j] = __builtin_amdgcn_mfma_f32_16x16x32_bf16(
                    af[i][s], bf[jh * 2 + j][s], acc[ih * 4 + i][jh * 2 + j], 0, 0, 0);
    __builtin_amdgcn_s_setprio(0);
}

__device__ __forceinline__ void gemm256_8ph(const u16* Abase, const u16* Bbase,
                                            u16* lds, int t,
                                            int arow, int brow, int co0, int co1,
                                            f32x4 acc[8][4]) {
    const int sr = t >> 3;
    const int sc = ((t & 7) ^ (sr & 7)) << 3;
    const u16* Ast = Abase + (long)sr * 1024 + sc;
    const u16* Bst = Bbase + (long)sr * 1024 + sc;
    u16* sA0 = lds;
    u16* sA1 = lds + 16384;
    u16* sB0 = lds + 32768;
    u16* sB1 = lds + 49152;

    s16x8 af[4][2], bf[4][2];

    // Prologue: E0.B, E0.A, O0.B (12 loads); vmcnt(4) -> E0 fully staged.
    stage_half64(Bst, sB0, 0, 0, t); stage_half64(Bst, sB0, 0, 1, t);
    stage_half64(Ast, sA0, 0, 0, t); stage_half64(Ast, sA0, 0, 1, t);
    stage_half64(Bst, sB1, 1, 0, t); stage_half64(Bst, sB1, 1, 1, t);
    asm volatile("s_waitcnt vmcnt(4)" ::: "memory");
    ABAR();

#pragma unroll 1
    for (int it = 0; it < 8; it++) {
        const int  tO   = 2 * it + 1;
        const bool more = (it < 7);
        // ph0: E q(0,0); reads A-lo + B01; stage O.A h0
        read_A8(sA0, arow, 0, co0, co1, af);
        read_B4(sB0, brow, 0, co0, co1, bf);
        stage_half64(Ast, sA1, tO, 0, t);
        mfma16q(acc, af, bf, 0, 0);
        ABAR();
        // ph1: E q(0,1); reads B23; stage O.A h1
        read_B4(sB0, brow, 1, co0, co1, bf);
        stage_half64(Ast, sA1, tO, 1, t);
        mfma16q(acc, af, bf, 0, 1);
        ABAR();
        // ph2: E q(1,0); reads A-hi; stage E'.B h0
        read_A8(sA0, arow, 1, co0, co1, af);
        if (more) stage_half64(Bst, sB0, tO + 1, 0, t);
        mfma16q(acc, af, bf, 1, 0);
        ABAR();
        // ph3: E q(1,1); stage E'.B h1; counted vmcnt (O fully staged)
        if (more) stage_half64(Bst, sB0, tO + 1, 1, t);
        mfma16q(acc, af, bf, 1, 1);
        if (more) asm volatile("s_waitcnt vmcnt(4)" ::: "memory");
        else      asm volatile("s_waitcnt vmcnt(0)" ::: "memory");
        ABAR();
        // ph4: O q(0,0); reads A-lo + B01; stage E'.A h0
        read_A8(sA1, arow, 0, co0, co1, af);
        read_B4(sB1, brow, 0, co0, co1, bf);
        if (more) stage_half64(Ast, sA0, tO + 1, 0, t);
        mfma16q(acc, af, bf, 0, 0);
        ABAR();
        // ph5: O q(0,1); reads B23; stage E'.A h1
        read_B4(sB1, brow, 1, co0, co1, bf);
        if (more) stage_half64(Ast, sA0, tO + 1, 1, t);
        mfma16q(acc, af, bf, 0, 1);
        ABAR();
        // ph6: O q(1,0); reads A-hi; stage O'.B h0
        read_A8(sA1, arow, 1, co0, co1, af);
        if (more) stage_half64(Bst, sB1, tO + 2, 0, t);
        mfma16q(acc, af, bf, 1, 0);
        ABAR();
        // ph7: O q(1,1); stage O'.B h1; counted vmcnt (E' staged)
        if (more) stage_half64(Bst, sB1, tO + 2, 1, t);
        mfma16q(acc, af, bf, 1, 1);
        if (more) asm volatile("s_waitcnt vmcnt(4)" ::: "memory");
        ABAR();
    }
}

// ---------------------------------------------------------------------------
// 8-phase 256x256 projection GEMM (validated R3/R5). grid 768 = exactly
// 3 rounds at 1 block/CU (128 KiB LDS).
// ---------------------------------------------------------------------------
__global__ __launch_bounds__(512, 2) void proj_all8(const u16* __restrict__ X,
                                                    const u16* __restrict__ Wqt,
                                                    const u16* __restrict__ Wkt,
                                                    const u16* __restrict__ Wvt,
                                                    u16* __restrict__ Qb,
                                                    u16* __restrict__ Kb,
                                                    u16* __restrict__ Vt) {
    __shared__ u16 lds[65536];                   // 128 KiB
    // XCD-chunked bijective swizzle: 768 = 8 x 96.
    const int bx  = ((blockIdx.x & 7) * 96) + (blockIdx.x >> 3);
    const int z   = bx >> 8;                     // 0:Q 1:K 2:V
    const int rem = bx & 255;
    const int m0  = (rem >> 2) << 8;
    const int n0  = (rem & 3) << 8;
    const u16* Wt = (z == 0) ? Wqt : (z == 1) ? Wkt : Wvt;

    const int t    = threadIdx.x;
    const int lane = t & 63, w = t >> 6;
    const int wr = w >> 2, wc = w & 3;           // 2M x 4N wave grid
    const int lm = lane & 15, lg = lane >> 4;
    const int arow = wr * 128 + lm;
    const int brow = wc * 64 + lm;
    const int co0 = ((lg) ^ (lm & 7)) << 3;
    const int co1 = ((4 + lg) ^ (lm & 7)) << 3;

    f32x4 acc[8][4] = {};
    gemm256_8ph(X + (long)m0 * 1024, Wt + (long)n0 * 1024, lds, t,
                arow, brow, co0, co1, acc);

    if (z < 2) {
        u16* O = (z == 0) ? Qb : Kb;
#pragma unroll
        for (int i = 0; i < 8; i++)
#pragma unroll
            for (int j = 0; j < 4; j++)
#pragma unroll
                for (int r = 0; r < 4; r++) {
                    int row = m0 + wr * 128 + i * 16 + lg * 4 + r;
                    int col = n0 + wc * 64 + j * 16 + lm;
                    O[(long)row * 1024 + col] = f2bf(acc[i][j][r]);
                }
    } else {
#pragma unroll
        for (int i = 0; i < 8; i++)
#pragma unroll
            for (int j = 0; j < 4; j++) {
                int row0 = m0 + wr * 128 + i * 16 + lg * 4;
                int col  = n0 + wc * 64 + j * 16 + lm;
                int b = row0 >> 12, s = row0 & 4095;
                s16x4 p0;
                p0.x = (short)f2bf(acc[i][j][0]); p0.y = (short)f2bf(acc[i][j][1]);
                p0.z = (short)f2bf(acc[i][j][2]); p0.w = (short)f2bf(acc[i][j][3]);
                *(s16x4*)&Vt[(long)b * 4194304 + (long)col * 4096 + s] = p0;
            }
    }
}

// ---------------------------------------------------------------------------
// Fused S-GEMM + softmax-numerator: P = exp(QK^T/32 - 16) (causal; fixed
// offset replaces the row max — scale-invariant, cancels in p/l). P written
// bf16 into packed lower-tri tiles; per-row sums accumulated into l[] via
// 16-lane shuffle reduction + one atomicAdd per row-quarter. grid 4*272.
// (R0/R5-proven form — best measured: 110.8-112.2 us.)
// ---------------------------------------------------------------------------
__global__ __launch_bounds__(256, 2) void sgemm_causal(const u16* __restrict__ Q,
                                                       const u16* __restrict__ K,
                                                       u16* __restrict__ S,
                                                       float* __restrict__ l) {
    __shared__ u16 sA[8192], sB[16384];
    int b  = blockIdx.x / 272;
    int tt = blockIdx.x % 272;
    int it = (int)(2.0f * sqrtf((float)tt + 1.0f)) - 1;
    if (it > 31) it = 31;
    if (it < 0) it = 0;
    while (it < 31 && (((it + 2) * (it + 2)) >> 2) <= tt) ++it;
    while (it > 0 && (((it + 1) * (it + 1)) >> 2) > tt) --it;
    int jp  = tt - (((it + 1) * (it + 1)) >> 2);
    int jt0 = jp * 2, jt1 = jt0 + 1;
    bool valid1 = (jt1 <= it);

    const u16* A  = Q + (long)b * 4194304;
    const u16* Kp = K + (long)b * 4194304;
    f32x4 acc0[4][4] = {}, acc1[4][4] = {};
    gemm_core64(A, 1024, Kp + (long)jt0 * 131072, Kp + (long)jt1 * 131072, 1024,
                it * 128, 1024, acc0, acc1, sA, sB);

    long tribase = (long)(b * 528 + ((it * (it + 1)) >> 1));
    u16* Sp0 = S + (tribase + jt0) * 16384;
    u16* Sp1 = S + (tribase + jt1) * 16384;
    int lane = threadIdx.x & 63, wave = threadIdx.x >> 6;
    int wm = (wave & 1) << 6, wn = (wave >> 1) << 6, lm = lane & 15, lg = lane >> 4;
    const float LOG2E = 1.44269504088896f;

    float rs[4][4];
#pragma unroll
    for (int i = 0; i < 4; i++)
#pragma unroll
        for (int r = 0; r < 4; r++) rs[i][r] = 0.0f;

#pragma unroll
    for (int i = 0; i < 4; i++)
#pragma unroll
        for (int j = 0; j < 4; j++)
#pragma unroll
            for (int r = 0; r < 4; r++) {
                int ri = wm + i * 16 + lg * 4 + r;
                int cj = wn + j * 16 + lm;
                int gi = it * 128 + ri;
                float p0 = (jt0 * 128 + cj > gi) ? 0.0f
                         : exp2f((acc0[i][j][r] * 0.03125f - 16.0f) * LOG2E);
                Sp0[ri * 128 + cj] = f2bf(p0);
                rs[i][r] += p0;
                if (valid1) {
                    float p1 = (jt1 * 128 + cj > gi) ? 0.0f
                             : exp2f((acc1[i][j][r] * 0.03125f - 16.0f) * LOG2E);
                    Sp1[ri * 128 + cj] = f2bf(p1);
                    rs[i][r] += p1;
                }
            }

#pragma unroll
    for (int i = 0; i < 4; i++)
#pragma unroll
        for (int r = 0; r < 4; r++) {
            float s = rs[i][r];
            s += __shfl_xor(s, 1, 64);
            s += __shfl_xor(s, 2, 64);
            s += __shfl_xor(s, 4, 64);
            s += __shfl_xor(s, 8, 64);
            if (lm == 0)
                atomicAdd(&l[b * 4096 + it * 128 + wm + i * 16 + lg * 4 + r], s);
        }
}

// ---------------------------------------------------------------------------
// O = P @ V: 128 rows x 256 cols per block, grid 512, balance-aware mapping
// (CU pairs block g with g+256: it sums to 31 — constant K-work per CU).
// Direct store scaled by 1/l. No atomics. (R0-R5-proven form; reverted from
// the R9 128x128 restructure which raised staging-per-MFMA 1.5x for no
// occupancy payoff.)
// ---------------------------------------------------------------------------
__global__ __launch_bounds__(256, 2) void pv_gemm(const u16* __restrict__ P,
                                                  const u16* __restrict__ Vt,
                                                  const float* __restrict__ l,
                                                  float* __restrict__ Out) {
    __shared__ u16 sA[8192], sB[16384];
    int g  = blockIdx.x;
    int it = (g < 256) ? (31 - (g >> 4)) : ((g - 256) >> 4);
    int rem = g & 15;
    int b   = rem >> 2;
    int atp = rem & 3;

    const int t    = threadIdx.x;
    const int lane = t & 63;
    const int wave = t >> 6;
    const int wm   = (wave & 1) << 6;
    const int wn   = (wave >> 1) << 6;
    const int lm   = lane & 15;
    const int lg   = lane >> 4;
    const int sr   = t >> 3;
    const int sc   = (((t & 7) ^ ((t >> 3) & 7)) << 3);

    const u16* Pbase = P + (long)(b * 528 + ((it * (it + 1)) >> 1)) * 16384;
    const u16* gA0 = Pbase + sr * 128 + sc;
    const u16* gB0 = Vt + (long)b * 4194304 + (long)(atp * 256 + sr) * 4096 + sc;
    const u16* gC0 = gB0 + (long)128 * 4096;

    f32x4 acc0[4][4] = {}, acc1[4][4] = {};
    for (int jt = 0; jt <= it; jt++) {
        long aoff = (long)jt * 16384;
        long boff = (long)jt * 128;
#pragma unroll
        for (int kk = 0; kk < 128; kk += 64)
            kstep64(gA0 + aoff + kk, gB0 + boff + kk, gC0 + boff + kk,
                    128, 4096, sA, sB, wm, wn, lm, lg, acc0, acc1);
    }

#pragma unroll
    for (int i = 0; i < 4; i++)
#pragma unroll
        for (int r = 0; r < 4; r++) {
            int gi = it * 128 + wm + i * 16 + lg * 4 + r;
            float scale = 1.0f / l[b * 4096 + gi];
#pragma unroll
            for (int j = 0; j < 4; j++) {
                int ga = atp * 256 + wn + j * 16 + lm;
                float* o = &Out[((long)b * 4096 + gi) * 1024 + ga];
                o[0]   = acc0[i][j][r] * scale;
                o[128] = acc1[i][j][r] * scale;
            }
        }
}

// ---------------------------------------------------------------------------
// Workspace layout (bytes):
//   Qb   [0,          33554432)
//   Kb   [33554432,   67108864)
//   Vt   [67108864,  100663296)
//   l    [100663296, 100728832)   fp32 row sums (atomic-accumulated)
//   Xb   [100728832, 134283264)   (dead after proj_all8)
//   Wqt/Wkt/Wvt [134283264, 140574720)  (dead after proj_all8)
//   S/P  [100728832, 169934848)   packed tri tiles (bf16 P), overlays Xb+W
// ---------------------------------------------------------------------------
extern "C" void kernel_launch(void* const* d_in, const int* in_sizes, int n_in,
                              void* d_out, int out_size, void* d_ws, size_t ws_size,
                              hipStream_t stream) {
    const float* X  = (const float*)d_in[0];
    const float* Wk = (const float*)d_in[1];
    const float* Wq = (const float*)d_in[2];
    const float* Wv = (const float*)d_in[3];
    float* Out = (float*)d_out;

    char* w = (char*)d_ws;
    u16*   Qb   = (u16*)(w);
    u16*   Kb   = (u16*)(w + 33554432);
    u16*   Vt   = (u16*)(w + 67108864);
    float* l    = (float*)(w + 100663296);
    u16*   Xb   = (u16*)(w + 100728832);
    u16*   Wqt  = (u16*)(w + 134283264);
    u16*   Wkt  = (u16*)(w + 136380416);
    u16*   Wvt  = (u16*)(w + 138477568);
    u16*   S    = (u16*)(w + 100728832);

    convert_all<<<17153, 256, 0, stream>>>(X, Wk, Wq, Wv, Xb, Wkt, Wqt, Wvt, l);
    proj_all8<<<768, 512, 0, stream>>>(Xb, Wqt, Wkt, Wvt, Qb, Kb, Vt);
    sgemm_causal<<<1088, 256, 0, stream>>>(Qb, Kb, S, l);
    pv_gemm<<<512, 256, 0, stream>>>(S, Vt, l, Out);
}